// Round 18
// baseline (194.817 us; speedup 1.0000x reference)
//
#include <hip/hip_runtime.h>
#include <stdint.h>

#define AS1 __attribute__((address_space(1)))
#define AS3 __attribute__((address_space(3)))

typedef __attribute__((ext_vector_type(8))) short bf16x8;
typedef __attribute__((ext_vector_type(4))) float f32x4;

// ================= Cl(4,1) ~= M4(C) isomorphism, built at compile time =================
struct Mono { int col[4]; int ph[4]; };

constexpr Mono mono_mul(Mono A, Mono B) {
    Mono R{};
    for (int r = 0; r < 4; ++r) {
        int k = A.col[r];
        R.col[r] = B.col[k];
        R.ph[r] = (A.ph[r] + B.ph[k]) & 3;
    }
    return R;
}

constexpr Mono gen(int g) {
    Mono E{};
    for (int r = 0; r < 4; ++r) {
        int r1 = (r >> 1) & 1, r0 = r & 1;
        if (g == 0)      { E.col[r] = r ^ 2; E.ph[r] = 0; }
        else if (g == 1) { E.col[r] = r ^ 2; E.ph[r] = r1 ? 1 : 3; }
        else if (g == 2) { E.col[r] = r ^ 1; E.ph[r] = r1 ? 2 : 0; }
        else if (g == 3) { E.col[r] = r ^ 1; E.ph[r] = ((r1 ? 2 : 0) + (r0 ? 1 : 3)) & 3; }
        else             { E.col[r] = r;     E.ph[r] = (1 + (r1 ? 2 : 0) + (r0 ? 2 : 0)) & 3; }
    }
    return E;
}

struct Blades { Mono m[32]; };
constexpr Blades make_blades() {
    Blades B{};
    for (int A = 0; A < 32; ++A) {
        Mono M{};
        for (int r = 0; r < 4; ++r) { M.col[r] = r; M.ph[r] = 0; }
        for (int g = 0; g < 5; ++g)
            if ((A >> g) & 1) M = mono_mul(M, gen(g));
        B.m[A] = M;
    }
    return B;
}
constexpr Blades BL = make_blades();

struct FwdTab { int bl[4][4][2][4]; float sg[4][4][2][4]; };
constexpr FwdTab make_fwd() {
    FwdTab T{};
    int cnt[4][4][2] = {};
    for (int A = 0; A < 32; ++A)
        for (int r = 0; r < 4; ++r) {
            int c = BL.m[A].col[r], p = BL.m[A].ph[r];
            int rc = p & 1;
            int& n = cnt[r][c][rc];
            T.bl[r][c][rc][n] = A;
            T.sg[r][c][rc][n] = (p & 2) ? -1.f : 1.f;
            ++n;
        }
    return T;
}
constexpr FwdTab FT = make_fwd();

__device__ inline unsigned short f2bf(float f) {
    uint32_t u = __float_as_uint(f);
    u += 0x7FFFu + ((u >> 16) & 1u);
    return (unsigned short)(u >> 16);
}

// ---- kernel 1 (fused transforms) ---- (unchanged from R16 checkpoint)
__global__ __launch_bounds__(256) void xform_kernel(const float* __restrict__ x,
                                                    const float* __restrict__ w,
                                                    unsigned short* __restrict__ Xb,
                                                    unsigned short* __restrict__ Wr) {
    __shared__ alignas(16) float XS[8192];   // 32 KB: 256 mv x 32 f32
    if (blockIdx.x < 2048) {
        int tid = threadIdx.x;
        const float4* xp = (const float4*)(x + (size_t)blockIdx.x * 8192);
        float4 ld[8];
#pragma unroll
        for (int r = 0; r < 8; ++r) ld[r] = xp[r * 256 + tid];   // coalesced
#pragma unroll
        for (int r = 0; r < 8; ++r) {
            int U = r * 256 + tid;
            int L = (U & ~7) | ((U & 7) ^ ((U >> 3) & 7));
            *(float4*)&XS[L * 4] = ld[r];
        }
        __syncthreads();
        float v[32];
#pragma unroll
        for (int q = 0; q < 8; ++q) {
            int L = tid * 8 + (q ^ (tid & 7));
            float4 f = *(const float4*)&XS[L * 4];
            v[q * 4 + 0] = f.x; v[q * 4 + 1] = f.y; v[q * 4 + 2] = f.z; v[q * 4 + 3] = f.w;
        }
        int t = blockIdx.x * 256 + tid;          // t = n*256 + i
        int i = t & 255, n = t >> 8;
#pragma unroll
        for (int b = 0; b < 4; ++b) {
            union { unsigned short s[8]; uint4 u; } r;
#pragma unroll
            for (int c = 0; c < 4; ++c)
#pragma unroll
                for (int rc = 0; rc < 2; ++rc) {
                    float s = 0.f;
#pragma unroll
                    for (int j = 0; j < 4; ++j)
                        s += FT.sg[c][b][rc][j] * v[FT.bl[c][b][rc][j]];
                    r.s[c * 2 + rc] = f2bf(s);
                }
            *((uint4*)(Xb + (size_t)(n * 4 + b) * 2048 + i * 8)) = r.u;
        }
    } else {
        int t = (blockIdx.x - 2048) * 256 + threadIdx.x;   // t = o*256 + i
        int i = t & 255, o = t >> 8;
        float v[32];
        const float4* wp = (const float4*)(w + (size_t)t * 32);
#pragma unroll
        for (int q = 0; q < 8; ++q) {
            float4 f = wp[q];
            v[q * 4 + 0] = f.x; v[q * 4 + 1] = f.y; v[q * 4 + 2] = f.z; v[q * 4 + 3] = f.w;
        }
        float Re[4][4], Im[4][4];
#pragma unroll
        for (int a = 0; a < 4; ++a)
#pragma unroll
            for (int c = 0; c < 4; ++c) {
                float sr = 0.f, si = 0.f;
#pragma unroll
                for (int j = 0; j < 4; ++j) {
                    sr += FT.sg[a][c][0][j] * v[FT.bl[a][c][0][j]];
                    si += FT.sg[a][c][1][j] * v[FT.bl[a][c][1][j]];
                }
                Re[a][c] = sr; Im[a][c] = si;
            }
#pragma unroll
        for (int ra = 0; ra < 2; ++ra)
#pragma unroll
            for (int a = 0; a < 4; ++a) {
                int m = o * 8 + ra * 4 + a;
                union { unsigned short s[8]; uint4 u; } r;
#pragma unroll
                for (int c = 0; c < 4; ++c) {
                    float v0 = ra == 0 ? Re[a][c] : Im[a][c];
                    float v1 = ra == 0 ? -Im[a][c] : Re[a][c];
                    r.s[c * 2 + 0] = f2bf(v0);
                    r.s[c * 2 + 1] = f2bf(v1);
                }
                *((uint4*)(Wr + (size_t)m * 2048 + i * 8)) = r.u;
            }
    }
}

// ---- kernel 2: R5 substrate + m201-style 2-phase/tile interleave ----
// C_virtual[2048,8192] = Wr * Xb^T.
// SUBSTRATE (R5/R16-proven, 82 µs): 4-buffer LDS ring (128 KiB), BK=32, 3-tile-deep
// global_load_lds prefetch, ONE counted s_waitcnt vmcnt(8) per tile (never 0 until the
// tail), conflict-free both-sides chunk swizzle, launch_bounds(512,2) (R13: (512,4)
// spills the 128-float acc -> 1.8 GB scratch; NEVER lower the VGPR cap).
// NEW (m201 phase granularity; R9's regression was shallow 2-buffer prefetch, fixed
// here by keeping the 4-ring): each tile's 32 MFMAs split into 2 phases of 16, each
// phase = {ds_read subtile (8 or 4 x b128) | issue 2 gload_lds of tile t+3 | barrier |
// setprio(1) 16 MFMA setprio(0) | barrier}. Unlocks the T3/T5 regime (m218b/m201).
// Race audit: intra-tile barriers are scheduling-only — ring slot (t+3)&3 is disjoint
// from the slot being read (t&3); publication of tile t = vmcnt(8)+barrier at tile
// start (all waves' own loads retired); tile t-1 readers finished before their MFMAs
// (data dep) which precede this tile's ISSUEs in barrier order.
// NOTE: all acc[][] indexing is compile-time (full unroll).
__global__ __launch_bounds__(512, 2) void gemm_kernel(const unsigned short* __restrict__ A,
                                                      const unsigned short* __restrict__ B,
                                                      float* __restrict__ out) {
    const int K = 2048;
    const int NT = 64;                         // K / 32
    __shared__ alignas(16) unsigned short SM[4 * 16384];   // 128 KB: 4 x (A 16KB + B 16KB)

    const int tid = threadIdx.x;
    const int wid = tid >> 6, lane = tid & 63;
    const int lm = lane & 15, quad = lane >> 4;
    const int wm = wid >> 2, wn = wid & 3;     // 2 x 4 wave grid
    const int row0 = blockIdx.y * 256;         // A rows (M = o*8+ra*4+a)
    const int col0 = blockIdx.x * 256;         // B rows (N = n*4+c)

    // staging source offsets: chunk g = p*512+tid; r=g>>2; c=g&3; src chunk = c^((r>>1)&3)
    size_t gA[2], gB[2];
    int ldsA[2], ldsB[2];
#pragma unroll
    for (int p = 0; p < 2; ++p) {
        int g = p * 512 + tid;
        int r = g >> 2, c = g & 3;
        int sc = c ^ ((r >> 1) & 3);
        gA[p] = (size_t)(row0 + r) * K + sc * 8;
        gB[p] = (size_t)(col0 + r) * K + sc * 8;
        ldsA[p] = (p * 512 + wid * 64) * 8;           // wave-uniform LDS base (shorts)
        ldsB[p] = 8192 + (p * 512 + wid * 64) * 8;
    }

    // fragment read offsets (swizzled to match): byte = row*64 + ((quad^((row>>1)&3))*16)
    const int swz = (lm >> 1) & 3;
    const int aoff = (wm * 128 + lm) * 32 + (quad ^ swz) * 8;
    const int boff = 8192 + (wn * 64 + lm) * 32 + (quad ^ swz) * 8;

    f32x4 acc[8][4];
#pragma unroll
    for (int i = 0; i < 8; ++i)
#pragma unroll
        for (int j = 0; j < 4; ++j) acc[i][j] = (f32x4){0.f, 0.f, 0.f, 0.f};

    auto ISSUE_A = [&](int t) {
        const int bb = (t & 3) * 16384;
        const int k0 = t * 32;
#pragma unroll
        for (int p = 0; p < 2; ++p)
            __builtin_amdgcn_global_load_lds((const AS1 void*)(A + gA[p] + k0),
                                             (AS3 void*)(&SM[bb + ldsA[p]]), 16, 0, 0);
    };
    auto ISSUE_B = [&](int t) {
        const int bb = (t & 3) * 16384;
        const int k0 = t * 32;
#pragma unroll
        for (int p = 0; p < 2; ++p)
            __builtin_amdgcn_global_load_lds((const AS1 void*)(B + gB[p] + k0),
                                             (AS3 void*)(&SM[bb + ldsB[p]]), 16, 0, 0);
    };

    // prologue: 3 K-tiles in flight (12 loads outstanding)
    ISSUE_A(0); ISSUE_B(0); ISSUE_A(1); ISSUE_B(1); ISSUE_A(2); ISSUE_B(2);

    for (int t = 0; t < NT; ++t) {
        const int bb = (t & 3) * 16384;
        // counted wait: own tile-t loads (oldest 4) retired; later tiles stay in flight
        if (t <= NT - 3)      asm volatile("s_waitcnt vmcnt(8)" ::: "memory");
        else if (t == NT - 2) asm volatile("s_waitcnt vmcnt(4)" ::: "memory");
        else                  asm volatile("s_waitcnt vmcnt(0)" ::: "memory");
        __builtin_amdgcn_s_barrier();          // tile t published to all waves
        bf16x8 a0[4], a1[4], bv[4];
        // ---- phase 0: 8 ds_read (B all + A fm0-3) | stage A-half of t+3 | 16 MFMA ----
#pragma unroll
        for (int fn = 0; fn < 4; ++fn) bv[fn] = *(const bf16x8*)&SM[bb + boff + fn * 512];
#pragma unroll
        for (int f = 0; f < 4; ++f) a0[f] = *(const bf16x8*)&SM[bb + aoff + f * 512];
        if (t < NT - 3) ISSUE_A(t + 3);        // writes slot (t-1)&3: readers done (see audit)
        __builtin_amdgcn_s_setprio(1);
#pragma unroll
        for (int f = 0; f < 4; ++f)
#pragma unroll
            for (int n = 0; n < 4; ++n)
                acc[f][n] = __builtin_amdgcn_mfma_f32_16x16x32_bf16(a0[f], bv[n],
                                                                    acc[f][n], 0, 0, 0);
        __builtin_amdgcn_s_setprio(0);
        __builtin_amdgcn_s_barrier();          // phase boundary (scheduling convoy)
        // ---- phase 1: 4 ds_read (A fm4-7) | stage B-half of t+3 | 16 MFMA ----
#pragma unroll
        for (int f = 0; f < 4; ++f) a1[f] = *(const bf16x8*)&SM[bb + aoff + (f + 4) * 512];
        if (t < NT - 3) ISSUE_B(t + 3);
        __builtin_amdgcn_s_setprio(1);
#pragma unroll
        for (int f = 0; f < 4; ++f)
#pragma unroll
            for (int n = 0; n < 4; ++n)
                acc[f + 4][n] = __builtin_amdgcn_mfma_f32_16x16x32_bf16(a1[f], bv[n],
                                                                        acc[f + 4][n], 0, 0, 0);
        __builtin_amdgcn_s_setprio(0);
        __builtin_amdgcn_s_barrier();          // tile boundary
    }
    __syncthreads();   // LDS reuse boundary: K-loop buffers -> per-wave epilogue scratch

    // ---- fused epilogue (R5/R16-verified): per-wave 32x64 f32 stripes, no x-wave sync ----
    float* scrw = (float*)SM + wid * 2048;     // 8 KB per wave (64 KB total)
    const int nl = lane >> 2, ol = lane & 3;   // 4 consecutive o's in adjacent lanes
#pragma unroll
    for (int s = 0; s < 4; ++s) {              // fm pair {2s, 2s+1} = C rows [s*32, s*32+32)
#pragma unroll
        for (int h = 0; h < 2; ++h)
#pragma unroll
            for (int fn = 0; fn < 4; ++fn)
#pragma unroll
                for (int r = 0; r < 4; ++r) {
                    int rw = h * 16 + quad * 4 + r;
                    int cc = (fn * 16 + lm) ^ (quad << 3);   // (rw>>2)&3 == quad
                    scrw[rw * 64 + cc] = acc[s * 2 + h][fn][r];
                }
        asm volatile("s_waitcnt lgkmcnt(0)" ::: "memory");
        float V[32];   // V[ra*16 + a*4 + c]
#pragma unroll
        for (int u = 0; u < 8; ++u) {          // u = ra*4 + a
            int row = ol * 8 + u;
            int cb = (nl * 4) ^ (((row >> 2) & 3) << 3);
            float4 f = *(const float4*)&scrw[row * 64 + cb];
            int vi = (u >> 2) * 16 + (u & 3) * 4;
            V[vi + 0] = f.x; V[vi + 1] = f.y; V[vi + 2] = f.z; V[vi + 3] = f.w;
        }
        float xa[32];
        float ss = 0.f;
#pragma unroll
        for (int Ab = 0; Ab < 32; ++Ab) {
            float sv = 0.f;
#pragma unroll
            for (int a = 0; a < 4; ++a) {
                const int c = BL.m[Ab].col[a];
                const int p = BL.m[Ab].ph[a];
                float vv = V[(p & 1) * 16 + a * 4 + c];
                sv += (p & 2) ? -vv : vv;
            }
            sv *= 0.25f;
            xa[Ab] = sv;
            ss += sv * sv;
        }
        float inv = rsqrtf(ss + 1e-6f);
        int o = (row0 >> 3) + wm * 16 + s * 4 + ol;
        int n = (col0 >> 2) + wn * 16 + nl;
        float4* op = (float4*)(out + ((size_t)n * 256 + o) * 32);
#pragma unroll
        for (int q = 0; q < 8; ++q) {
            float4 f;
            f.x = xa[q * 4 + 0] * inv; f.y = xa[q * 4 + 1] * inv;
            f.z = xa[q * 4 + 2] * inv; f.w = xa[q * 4 + 3] * inv;
            op[q] = f;
        }
        asm volatile("s_waitcnt lgkmcnt(0)" ::: "memory");   // stripe reads done before rewrite
    }
}

extern "C" void kernel_launch(void* const* d_in, const int* in_sizes, int n_in,
                              void* d_out, int out_size, void* d_ws, size_t ws_size,
                              hipStream_t stream) {
    const float* x = (const float*)d_in[0];   // [4,512,256,32]
    const float* w = (const float*)d_in[1];   // [256,256,32]
    float* out = (float*)d_out;               // [4,512,256,32]

    unsigned short* Wr = (unsigned short*)d_ws;                             //  8,388,608 B
    unsigned short* Xb = (unsigned short*)((char*)d_ws + 8388608);          // 33,554,432 B

    hipLaunchKernelGGL(xform_kernel, dim3(2304),  dim3(256), 0, stream, x, w, Xb, Wr);
    hipLaunchKernelGGL(gemm_kernel,  dim3(32, 8), dim3(512), 0, stream, Wr, Xb, out);
}

// Round 21
// 191.935 us; speedup vs baseline: 1.0150x; 1.0150x over previous
//
#include <hip/hip_runtime.h>
#include <stdint.h>

#define AS1 __attribute__((address_space(1)))
#define AS3 __attribute__((address_space(3)))

typedef __attribute__((ext_vector_type(8))) short bf16x8;
typedef __attribute__((ext_vector_type(4))) float f32x4;

// ================= Cl(4,1) ~= M4(C) isomorphism, built at compile time =================
struct Mono { int col[4]; int ph[4]; };

constexpr Mono mono_mul(Mono A, Mono B) {
    Mono R{};
    for (int r = 0; r < 4; ++r) {
        int k = A.col[r];
        R.col[r] = B.col[k];
        R.ph[r] = (A.ph[r] + B.ph[k]) & 3;
    }
    return R;
}

constexpr Mono gen(int g) {
    Mono E{};
    for (int r = 0; r < 4; ++r) {
        int r1 = (r >> 1) & 1, r0 = r & 1;
        if (g == 0)      { E.col[r] = r ^ 2; E.ph[r] = 0; }
        else if (g == 1) { E.col[r] = r ^ 2; E.ph[r] = r1 ? 1 : 3; }
        else if (g == 2) { E.col[r] = r ^ 1; E.ph[r] = r1 ? 2 : 0; }
        else if (g == 3) { E.col[r] = r ^ 1; E.ph[r] = ((r1 ? 2 : 0) + (r0 ? 1 : 3)) & 3; }
        else             { E.col[r] = r;     E.ph[r] = (1 + (r1 ? 2 : 0) + (r0 ? 2 : 0)) & 3; }
    }
    return E;
}

struct Blades { Mono m[32]; };
constexpr Blades make_blades() {
    Blades B{};
    for (int A = 0; A < 32; ++A) {
        Mono M{};
        for (int r = 0; r < 4; ++r) { M.col[r] = r; M.ph[r] = 0; }
        for (int g = 0; g < 5; ++g)
            if ((A >> g) & 1) M = mono_mul(M, gen(g));
        B.m[A] = M;
    }
    return B;
}
constexpr Blades BL = make_blades();

struct FwdTab { int bl[4][4][2][4]; float sg[4][4][2][4]; };
constexpr FwdTab make_fwd() {
    FwdTab T{};
    int cnt[4][4][2] = {};
    for (int A = 0; A < 32; ++A)
        for (int r = 0; r < 4; ++r) {
            int c = BL.m[A].col[r], p = BL.m[A].ph[r];
            int rc = p & 1;
            int& n = cnt[r][c][rc];
            T.bl[r][c][rc][n] = A;
            T.sg[r][c][rc][n] = (p & 2) ? -1.f : 1.f;
            ++n;
        }
    return T;
}
constexpr FwdTab FT = make_fwd();

__device__ inline unsigned short f2bf(float f) {
    uint32_t u = __float_as_uint(f);
    u += 0x7FFFu + ((u >> 16) & 1u);
    return (unsigned short)(u >> 16);
}

// ---- kernel 1 (fused transforms) ---- (R16 checkpoint, unchanged)
__global__ __launch_bounds__(256) void xform_kernel(const float* __restrict__ x,
                                                    const float* __restrict__ w,
                                                    unsigned short* __restrict__ Xb,
                                                    unsigned short* __restrict__ Wr) {
    __shared__ alignas(16) float XS[8192];   // 32 KB: 256 mv x 32 f32
    if (blockIdx.x < 2048) {
        int tid = threadIdx.x;
        const float4* xp = (const float4*)(x + (size_t)blockIdx.x * 8192);
        float4 ld[8];
#pragma unroll
        for (int r = 0; r < 8; ++r) ld[r] = xp[r * 256 + tid];   // coalesced
#pragma unroll
        for (int r = 0; r < 8; ++r) {
            int U = r * 256 + tid;
            int L = (U & ~7) | ((U & 7) ^ ((U >> 3) & 7));
            *(float4*)&XS[L * 4] = ld[r];
        }
        __syncthreads();
        float v[32];
#pragma unroll
        for (int q = 0; q < 8; ++q) {
            int L = tid * 8 + (q ^ (tid & 7));
            float4 f = *(const float4*)&XS[L * 4];
            v[q * 4 + 0] = f.x; v[q * 4 + 1] = f.y; v[q * 4 + 2] = f.z; v[q * 4 + 3] = f.w;
        }
        int t = blockIdx.x * 256 + tid;          // t = n*256 + i
        int i = t & 255, n = t >> 8;
#pragma unroll
        for (int b = 0; b < 4; ++b) {
            union { unsigned short s[8]; uint4 u; } r;
#pragma unroll
            for (int c = 0; c < 4; ++c)
#pragma unroll
                for (int rc = 0; rc < 2; ++rc) {
                    float s = 0.f;
#pragma unroll
                    for (int j = 0; j < 4; ++j)
                        s += FT.sg[c][b][rc][j] * v[FT.bl[c][b][rc][j]];
                    r.s[c * 2 + rc] = f2bf(s);
                }
            *((uint4*)(Xb + (size_t)(n * 4 + b) * 2048 + i * 8)) = r.u;
        }
    } else {
        int t = (blockIdx.x - 2048) * 256 + threadIdx.x;   // t = o*256 + i
        int i = t & 255, o = t >> 8;
        float v[32];
        const float4* wp = (const float4*)(w + (size_t)t * 32);
#pragma unroll
        for (int q = 0; q < 8; ++q) {
            float4 f = wp[q];
            v[q * 4 + 0] = f.x; v[q * 4 + 1] = f.y; v[q * 4 + 2] = f.z; v[q * 4 + 3] = f.w;
        }
        float Re[4][4], Im[4][4];
#pragma unroll
        for (int a = 0; a < 4; ++a)
#pragma unroll
            for (int c = 0; c < 4; ++c) {
                float sr = 0.f, si = 0.f;
#pragma unroll
                for (int j = 0; j < 4; ++j) {
                    sr += FT.sg[a][c][0][j] * v[FT.bl[a][c][0][j]];
                    si += FT.sg[a][c][1][j] * v[FT.bl[a][c][1][j]];
                }
                Re[a][c] = sr; Im[a][c] = si;
            }
#pragma unroll
        for (int ra = 0; ra < 2; ++ra)
#pragma unroll
            for (int a = 0; a < 4; ++a) {
                int m = o * 8 + ra * 4 + a;
                union { unsigned short s[8]; uint4 u; } r;
#pragma unroll
                for (int c = 0; c < 4; ++c) {
                    float v0 = ra == 0 ? Re[a][c] : Im[a][c];
                    float v1 = ra == 0 ? -Im[a][c] : Re[a][c];
                    r.s[c * 2 + 0] = f2bf(v0);
                    r.s[c * 2 + 1] = f2bf(v1);
                }
                *((uint4*)(Wr + (size_t)m * 2048 + i * 8)) = r.u;
            }
    }
}

// ---- kernel 2: R16-checkpoint gemm (measured 82 µs, MfmaUtil 35%), minus setprio ----
// C_virtual[2048,8192] = Wr * Xb^T.  4-buffer LDS ring (128 KiB), BK=32, 3-tile-deep
// global_load_lds prefetch, ONE counted s_waitcnt vmcnt(8) + ONE barrier per tile
// (never drained to 0 until the tail), both-sides chunk swizzle, launch_bounds(512,2).
// SCHEDULE AVENUE CLOSED (R9: 4-phase −19%; R18: 2-phase −21% — every added barrier
// at 1 block/CU is an unfillable convoy). R13: (512,4) caps VGPR at 64 and spills the
// 128-float acc (1.8 GB scratch, 5x) — NEVER lower the VGPR cap.
// This round's delta: setprio REMOVED from the K-loop (m190: setprio slightly hurts
// non-8-phase GEMM, −1.5%). Everything else identical to the R16 checkpoint.
// NOTE: all acc[][] indexing is compile-time (full unroll).
__global__ __launch_bounds__(512, 2) void gemm_kernel(const unsigned short* __restrict__ A,
                                                      const unsigned short* __restrict__ B,
                                                      float* __restrict__ out) {
    const int K = 2048;
    const int NT = 64;                         // K / 32
    __shared__ alignas(16) unsigned short SM[4 * 16384];   // 128 KB: 4 x (A 8KB + B 8KB)

    const int tid = threadIdx.x;
    const int wid = tid >> 6, lane = tid & 63;
    const int lm = lane & 15, quad = lane >> 4;
    const int wm = wid >> 2, wn = wid & 3;     // 2 x 4 wave grid
    const int row0 = blockIdx.y * 256;         // A rows (M = o*8+ra*4+a)
    const int col0 = blockIdx.x * 256;         // B rows (N = n*4+c)

    // staging source offsets: chunk g = p*512+tid; r=g>>2; c=g&3; src chunk = c^((r>>1)&3)
    size_t gA[2], gB[2];
    int ldsA[2], ldsB[2];
#pragma unroll
    for (int p = 0; p < 2; ++p) {
        int g = p * 512 + tid;
        int r = g >> 2, c = g & 3;
        int sc = c ^ ((r >> 1) & 3);
        gA[p] = (size_t)(row0 + r) * K + sc * 8;
        gB[p] = (size_t)(col0 + r) * K + sc * 8;
        ldsA[p] = (p * 512 + wid * 64) * 8;           // wave-uniform LDS base (shorts)
        ldsB[p] = 8192 + (p * 512 + wid * 64) * 8;
    }

    // fragment read offsets (swizzled to match): byte = row*64 + ((quad^((row>>1)&3))*16)
    const int swz = (lm >> 1) & 3;
    const int aoff = (wm * 128 + lm) * 32 + (quad ^ swz) * 8;
    const int boff = 8192 + (wn * 64 + lm) * 32 + (quad ^ swz) * 8;

    f32x4 acc[8][4];
#pragma unroll
    for (int i = 0; i < 8; ++i)
#pragma unroll
        for (int j = 0; j < 4; ++j) acc[i][j] = (f32x4){0.f, 0.f, 0.f, 0.f};

    auto ISSUE = [&](int t) {
        const int bb = (t & 3) * 16384;
        const int k0 = t * 32;
#pragma unroll
        for (int p = 0; p < 2; ++p) {
            __builtin_amdgcn_global_load_lds((const AS1 void*)(A + gA[p] + k0),
                                             (AS3 void*)(&SM[bb + ldsA[p]]), 16, 0, 0);
            __builtin_amdgcn_global_load_lds((const AS1 void*)(B + gB[p] + k0),
                                             (AS3 void*)(&SM[bb + ldsB[p]]), 16, 0, 0);
        }
    };
    auto COMPUTE = [&](int t) {
        const int bb = (t & 3) * 16384;
        bf16x8 av[8], bv[4];
#pragma unroll
        for (int fn = 0; fn < 4; ++fn) bv[fn] = *(const bf16x8*)&SM[bb + boff + fn * 512];
#pragma unroll
        for (int fm = 0; fm < 8; ++fm) av[fm] = *(const bf16x8*)&SM[bb + aoff + fm * 512];
#pragma unroll
        for (int fm = 0; fm < 8; ++fm)
#pragma unroll
            for (int fn = 0; fn < 4; ++fn)
                acc[fm][fn] = __builtin_amdgcn_mfma_f32_16x16x32_bf16(av[fm], bv[fn],
                                                                      acc[fm][fn], 0, 0, 0);
    };

    // prologue: 3 K-tiles in flight
    ISSUE(0); ISSUE(1); ISSUE(2);
    for (int t = 0; t < NT - 3; ++t) {
        asm volatile("s_waitcnt vmcnt(8)" ::: "memory");   // tile t resident; t+1,t+2 in flight
        __builtin_amdgcn_s_barrier();
        ISSUE(t + 3);                                       // overwrites buf (t-1)&3: safe, all
        COMPUTE(t);                                         // readers consumed it before barrier
    }
    asm volatile("s_waitcnt vmcnt(8)" ::: "memory");
    __builtin_amdgcn_s_barrier();
    COMPUTE(NT - 3);
    asm volatile("s_waitcnt vmcnt(4)" ::: "memory");
    __builtin_amdgcn_s_barrier();
    COMPUTE(NT - 2);
    asm volatile("s_waitcnt vmcnt(0)" ::: "memory");
    __builtin_amdgcn_s_barrier();
    COMPUTE(NT - 1);
    __syncthreads();   // LDS reuse boundary: K-loop buffers -> per-wave epilogue scratch

    // ---- fused epilogue (R5/R16-verified): per-wave 32x64 f32 stripes, no x-wave sync ----
    float* scrw = (float*)SM + wid * 2048;     // 8 KB per wave (64 KB total)
    const int nl = lane >> 2, ol = lane & 3;   // 4 consecutive o's in adjacent lanes
#pragma unroll
    for (int s = 0; s < 4; ++s) {              // fm pair {2s, 2s+1} = C rows [s*32, s*32+32)
#pragma unroll
        for (int h = 0; h < 2; ++h)
#pragma unroll
            for (int fn = 0; fn < 4; ++fn)
#pragma unroll
                for (int r = 0; r < 4; ++r) {
                    int rw = h * 16 + quad * 4 + r;
                    int cc = (fn * 16 + lm) ^ (quad << 3);   // (rw>>2)&3 == quad
                    scrw[rw * 64 + cc] = acc[s * 2 + h][fn][r];
                }
        asm volatile("s_waitcnt lgkmcnt(0)" ::: "memory");
        float V[32];   // V[ra*16 + a*4 + c]
#pragma unroll
        for (int u = 0; u < 8; ++u) {          // u = ra*4 + a
            int row = ol * 8 + u;
            int cb = (nl * 4) ^ (((row >> 2) & 3) << 3);
            float4 f = *(const float4*)&scrw[row * 64 + cb];
            int vi = (u >> 2) * 16 + (u & 3) * 4;
            V[vi + 0] = f.x; V[vi + 1] = f.y; V[vi + 2] = f.z; V[vi + 3] = f.w;
        }
        float xa[32];
        float ss = 0.f;
#pragma unroll
        for (int Ab = 0; Ab < 32; ++Ab) {
            float sv = 0.f;
#pragma unroll
            for (int a = 0; a < 4; ++a) {
                const int c = BL.m[Ab].col[a];
                const int p = BL.m[Ab].ph[a];
                float vv = V[(p & 1) * 16 + a * 4 + c];
                sv += (p & 2) ? -vv : vv;
            }
            sv *= 0.25f;
            xa[Ab] = sv;
            ss += sv * sv;
        }
        float inv = rsqrtf(ss + 1e-6f);
        int o = (row0 >> 3) + wm * 16 + s * 4 + ol;
        int n = (col0 >> 2) + wn * 16 + nl;
        float4* op = (float4*)(out + ((size_t)n * 256 + o) * 32);
#pragma unroll
        for (int q = 0; q < 8; ++q) {
            float4 f;
            f.x = xa[q * 4 + 0] * inv; f.y = xa[q * 4 + 1] * inv;
            f.z = xa[q * 4 + 2] * inv; f.w = xa[q * 4 + 3] * inv;
            op[q] = f;
        }
        asm volatile("s_waitcnt lgkmcnt(0)" ::: "memory");   // stripe reads done before rewrite
    }
}

extern "C" void kernel_launch(void* const* d_in, const int* in_sizes, int n_in,
                              void* d_out, int out_size, void* d_ws, size_t ws_size,
                              hipStream_t stream) {
    const float* x = (const float*)d_in[0];   // [4,512,256,32]
    const float* w = (const float*)d_in[1];   // [256,256,32]
    float* out = (float*)d_out;               // [4,512,256,32]

    unsigned short* Wr = (unsigned short*)d_ws;                             //  8,388,608 B
    unsigned short* Xb = (unsigned short*)((char*)d_ws + 8388608);          // 33,554,432 B

    hipLaunchKernelGGL(xform_kernel, dim3(2304),  dim3(256), 0, stream, x, w, Xb, Wr);
    hipLaunchKernelGGL(gemm_kernel,  dim3(32, 8), dim3(512), 0, stream, Wr, Xb, out);
}